// Round 5
// baseline (115406.055 us; speedup 1.0000x reference)
//
#include <hip/hip_runtime.h>
#include <hip/hip_bf16.h>

// LSTM: V=50000, E=512, H=512, S=16384, batch=1.
// Phase 1: gx GEMM (fp32, bf16 store, permuted for 16 ranks x 32 units).
// Phase 2: 128 wgs launched; first 16 to register on one XCD participate.
//          h exchange = tag-in-data u64, fast path sc0 (same-XCD L2) with
//          agent-scope mirror fallback. Wave 0 polls, LDS broadcast.
// Phase 3: head MLP on rank 0.

#define S_LEN  16384
#define HID    512
#define NWG    16     // participants
#define NLAUNCH 128   // launched wgs (election pool)
#define NTHR   512
#define N_FAST 24     // fast poll attempts before agent fallback

typedef unsigned long long u64;

static __device__ __forceinline__ float bf2f(unsigned short u) {
  union { unsigned int i; float f; } v; v.i = ((unsigned int)u) << 16; return v.f;
}
static __device__ __forceinline__ unsigned short f2bf(float f) {
  union { float f; unsigned int i; } v; v.f = f;
  unsigned int r = v.i + 0x7fffu + ((v.i >> 16) & 1u);
  return (unsigned short)(r >> 16);
}
static __device__ __forceinline__ float fsig(float x) { return 1.f / (1.f + __expf(-x)); }
static __device__ __forceinline__ float ftanh(float x) { return 2.f / (1.f + __expf(-2.f * x)) - 1.f; }

// slot(k) = (k&7)*64 + (k>>3);  reader lane l, word i  <->  k = l*8+i, slot = i*64+l
static __device__ __forceinline__ int hslot(int k) { return (k & 7) * 64 + (k >> 3); }

// 8 batched sc0 loads (bypass L1, hit same-XCD L2), one vmcnt wait.
static __device__ __forceinline__ void poll8_fast(const u64* base, int lane, u64 v[8]) {
  u64 a = (u64)base + (u64)lane * 8ull;
  asm volatile(
      "global_load_dwordx2 %[v0], %[ad], off sc0\n\t"
      "global_load_dwordx2 %[v1], %[ad], off offset:512 sc0\n\t"
      "global_load_dwordx2 %[v2], %[ad], off offset:1024 sc0\n\t"
      "global_load_dwordx2 %[v3], %[ad], off offset:1536 sc0\n\t"
      "global_load_dwordx2 %[v4], %[ad], off offset:2048 sc0\n\t"
      "global_load_dwordx2 %[v5], %[ad], off offset:2560 sc0\n\t"
      "global_load_dwordx2 %[v6], %[ad], off offset:3072 sc0\n\t"
      "global_load_dwordx2 %[v7], %[ad], off offset:3584 sc0\n\t"
      "s_waitcnt vmcnt(0)"
      : [v0] "=&v"(v[0]), [v1] "=&v"(v[1]), [v2] "=&v"(v[2]), [v3] "=&v"(v[3]),
        [v4] "=&v"(v[4]), [v5] "=&v"(v[5]), [v6] "=&v"(v[6]), [v7] "=&v"(v[7])
      : [ad] "v"(a)
      : "memory");
}
static __device__ __forceinline__ void store_fast(u64* p, u64 w) {
  asm volatile("global_store_dwordx2 %[ad], %[vl], off sc0"
               :: [ad] "v"((u64)p), [vl] "v"(w) : "memory");
}

// ---------------- Phase 1: gx GEMM ----------------
// Store permuted: gx[t][ w*128 + gate*32 + jl ], w=(c&511)>>5, gate=c>>9, jl=c&31.
__global__ __launch_bounds__(256, 2) void gx_gemm(
    const int* __restrict__ x, const float* __restrict__ emb,
    const float* __restrict__ W_ih, const float* __restrict__ b_ih,
    const float* __restrict__ b_hh, unsigned short* __restrict__ gx)
{
  __shared__ float As[64][40];
  __shared__ float Bs[64][40];
  __shared__ int   xs[64];

  const int tid = threadIdx.x;
  const int bm = blockIdx.x;
  const int bn = blockIdx.y;

  if (tid < 64) xs[tid] = x[bm * 64 + tid];
  __syncthreads();

  float acc[4][4] = {};
  const int r0 = (tid >> 4) * 4;
  const int c0 = tid & 15;

  for (int kc = 0; kc < 512; kc += 32) {
#pragma unroll
    for (int h = 0; h < 2; ++h) {
      const int v = tid + h * 256;
      const int row = v >> 3, k4 = v & 7;
      const float4 av = *(const float4*)(emb + (size_t)xs[row] * 512 + kc + k4 * 4);
      As[row][k4 * 4 + 0] = av.x; As[row][k4 * 4 + 1] = av.y;
      As[row][k4 * 4 + 2] = av.z; As[row][k4 * 4 + 3] = av.w;
      const float4 bv = *(const float4*)(W_ih + (size_t)(bn * 64 + row) * 512 + kc + k4 * 4);
      Bs[row][k4 * 4 + 0] = bv.x; Bs[row][k4 * 4 + 1] = bv.y;
      Bs[row][k4 * 4 + 2] = bv.z; Bs[row][k4 * 4 + 3] = bv.w;
    }
    __syncthreads();
#pragma unroll
    for (int k4 = 0; k4 < 8; ++k4) {
      float4 a[4], b[4];
#pragma unroll
      for (int i = 0; i < 4; ++i) a[i] = *(const float4*)&As[r0 + i][k4 * 4];
#pragma unroll
      for (int j = 0; j < 4; ++j) b[j] = *(const float4*)&Bs[c0 + j * 16][k4 * 4];
#pragma unroll
      for (int i = 0; i < 4; ++i)
#pragma unroll
        for (int j = 0; j < 4; ++j) {
          acc[i][j] = __builtin_fmaf(a[i].x, b[j].x, acc[i][j]);
          acc[i][j] = __builtin_fmaf(a[i].y, b[j].y, acc[i][j]);
          acc[i][j] = __builtin_fmaf(a[i].z, b[j].z, acc[i][j]);
          acc[i][j] = __builtin_fmaf(a[i].w, b[j].w, acc[i][j]);
        }
    }
    __syncthreads();
  }

#pragma unroll
  for (int j = 0; j < 4; ++j) {
    const int c = bn * 64 + c0 + j * 16;
    const float bias = b_ih[c] + b_hh[c];
    const size_t dstc = (size_t)((c & 511) >> 5) * 128 + (size_t)(c >> 9) * 32 + (c & 31);
#pragma unroll
    for (int i = 0; i < 4; ++i) {
      const size_t t = (size_t)bm * 64 + r0 + i;
      gx[t * 2048 + dstc] = f2bf(acc[i][j] + bias);
    }
  }
}

// ---------------- Phase 2: XCD-pinned recurrence ----------------
__global__ __launch_bounds__(NTHR, 2) void lstm_rec(
    const float* __restrict__ W_hh, const unsigned short* __restrict__ gx,
    const float* __restrict__ W1, const float* __restrict__ b1,
    const float* __restrict__ W2, const float* __restrict__ b2,
    float* __restrict__ out,
    u64* __restrict__ h_fast,   // [2][512] (tag,val) — sc0 / same-XCD L2
    u64* __restrict__ h_slow,   // [2][512] (tag,val) — agent mirror
    unsigned int* __restrict__ elect)  // [8] cnt per xcd, [8]=winner+1
{
  const int tid = threadIdx.x;

  // ---- election: first NWG wgs registering on one XCD participate ----
  __shared__ int role_sh;
  if (tid == 0) {
    unsigned xcc;
    asm volatile("s_getreg_b32 %0, hwreg(HW_REG_XCC_ID)" : "=s"(xcc));
    xcc &= 7u;
    const unsigned r = __hip_atomic_fetch_add(&elect[xcc], 1u,
                         __ATOMIC_RELAXED, __HIP_MEMORY_SCOPE_AGENT);
    int role = -1;
    if (r < NWG) {
      if (r == NWG - 1) {
        unsigned exp = 0u;
        __hip_atomic_compare_exchange_strong(&elect[8], &exp, xcc + 1u,
            __ATOMIC_RELAXED, __ATOMIC_RELAXED, __HIP_MEMORY_SCOPE_AGENT);
      }
      unsigned wv;
      do {
        wv = __hip_atomic_load(&elect[8], __ATOMIC_RELAXED, __HIP_MEMORY_SCOPE_AGENT);
        if (wv == 0u) __builtin_amdgcn_s_sleep(2);
      } while (wv == 0u);
      if (wv == xcc + 1u) role = (int)r;
    }
    role_sh = role;
  }
  __syncthreads();
  const int w = role_sh;
  if (w < 0) return;

  const int s  = tid & 31;    // K-slice: k in [s*16, s*16+16)
  const int rg = tid >> 5;    // rows rg*8 .. rg*8+7 of this wg's 128 gate rows
  const int lane = tid & 63;

  // W_hh slice in VGPRs: 8 rows x 16 k.
  float wreg[8][16];
#pragma unroll
  for (int q = 0; q < 8; ++q) {
    const int r = rg * 8 + q;
    const int gate = r >> 5;
    const int jl = r & 31;
    const float* src = W_hh + ((size_t)(gate * 512 + w * 32 + jl)) * 512 + s * 16;
#pragma unroll
    for (int i4 = 0; i4 < 4; ++i4) {
      const float4 v = *(const float4*)(src + i4 * 4);
      wreg[q][i4 * 4 + 0] = v.x; wreg[q][i4 * 4 + 1] = v.y;
      wreg[q][i4 * 4 + 2] = v.z; wreg[q][i4 * 4 + 3] = v.w;
    }
  }

  __shared__ float dot_lds[128];
  __shared__ float hbuf[576];            // h[k] at k + (k>>3)  (pad per 8)
  __shared__ unsigned short gx_lds[2][128];

  float c_reg = 0.f;                     // lanes 0..31 of wave 0
  float h_reg[16];
#pragma unroll
  for (int i = 0; i < 16; ++i) h_reg[i] = 0.f;

  unsigned short gpre = 0;
  if (tid < 128) {
    gx_lds[0][tid] = gx[(size_t)0 * 2048 + w * 128 + tid];
    gpre = gx[(size_t)1 * 2048 + w * 128 + tid];
  }
  __syncthreads();

  for (int t = 0; t < S_LEN; ++t) {
    unsigned short gnew = 0;
    if (tid < 128 && t + 2 < S_LEN)
      gnew = gx[(size_t)(t + 2) * 2048 + w * 128 + tid];
    if (tid < 128 && t + 1 < S_LEN)
      gx_lds[(t + 1) & 1][tid] = gpre;
    gpre = gnew;

    float acc[8];
#pragma unroll
    for (int q = 0; q < 8; ++q) {
      float a = 0.f;
#pragma unroll
      for (int i = 0; i < 16; ++i) a = __builtin_fmaf(wreg[q][i], h_reg[i], a);
      acc[q] = a;
    }
#pragma unroll
    for (int q = 0; q < 8; ++q) {
      float a = acc[q];
      a += __shfl_xor(a, 1);
      a += __shfl_xor(a, 2);
      a += __shfl_xor(a, 4);
      a += __shfl_xor(a, 8);
      a += __shfl_xor(a, 16);
      acc[q] = a;
    }
    if (s == 0) {
#pragma unroll
      for (int q = 0; q < 8; ++q) dot_lds[rg * 8 + q] = acc[q];
    }
    __syncthreads();  // A — dots visible to wave 0

    if (tid < 64) {
      const int buf = (t + 1) & 1;
      // gates on lanes 0..31 (unit w*32+lane)
      if (lane < 32) {
        const int jl = lane;
        const int tb = t & 1;
        const float pi = dot_lds[jl]      + bf2f(gx_lds[tb][jl]);
        const float pf = dot_lds[32 + jl] + bf2f(gx_lds[tb][32 + jl]);
        const float pg = dot_lds[64 + jl] + bf2f(gx_lds[tb][64 + jl]);
        const float po = dot_lds[96 + jl] + bf2f(gx_lds[tb][96 + jl]);
        const float ig = fsig(pi), fg = fsig(pf), gg = ftanh(pg), og = fsig(po);
        c_reg = fg * c_reg + ig * gg;
        const float hv = og * ftanh(c_reg);

        union { float f; unsigned int u; } hu; hu.f = hv;
        const u64 word = ((u64)(unsigned)(t + 1) << 32) | (u64)hu.u;
        const int slot = hslot(w * 32 + jl);
        store_fast(&h_fast[buf * 512 + slot], word);
        __hip_atomic_store(&h_slow[buf * 512 + slot], word,
                           __ATOMIC_RELAXED, __HIP_MEMORY_SCOPE_AGENT);
      }

      // poll h_{t+1}: lane l gets k = l*8+i
      if (t + 1 < S_LEN) {
        const unsigned want = (unsigned)(t + 1);
        u64 v[8];
        bool done = false;
        for (int it = 0; it < N_FAST && !done; ++it) {
          poll8_fast(h_fast + buf * 512, lane, v);
          bool ok = true;
#pragma unroll
          for (int i = 0; i < 8; ++i) ok &= ((unsigned)(v[i] >> 32) == want);
          done = __all(ok);
        }
        if (!done) {
          const u64* hb = h_slow + buf * 512;
          for (;;) {
#pragma unroll
            for (int i = 0; i < 8; ++i)
              v[i] = __hip_atomic_load(&hb[i * 64 + lane],
                                       __ATOMIC_RELAXED, __HIP_MEMORY_SCOPE_AGENT);
            bool ok = true;
#pragma unroll
            for (int i = 0; i < 8; ++i) ok &= ((unsigned)(v[i] >> 32) == want);
            if (__all(ok)) break;
            __builtin_amdgcn_s_sleep(1);
          }
        }
#pragma unroll
        for (int i = 0; i < 8; ++i) {
          union { unsigned int u; float f; } hu; hu.u = (unsigned)v[i];
          hbuf[lane * 9 + i] = hu.f;   // k=lane*8+i at k+(k>>3)
        }
      }
    }
    __syncthreads();  // B — h_{t+1} staged in LDS

    if (t + 1 < S_LEN) {
#pragma unroll
      for (int i = 0; i < 16; ++i) {
        const int k = s * 16 + i;
        h_reg[i] = hbuf[k + (k >> 3)];
      }
    }
  }

  // ---------------- Phase 3: head (rank 0) ----------------
  if (w == 0) {
    __shared__ float hl[512];
    __shared__ float zl[128];
    {
      // final h_S: tag S in slow buf 0 (S even)
      const int slot = hslot(tid);
      u64 v;
      do {
        v = __hip_atomic_load(&h_slow[slot], __ATOMIC_RELAXED, __HIP_MEMORY_SCOPE_AGENT);
      } while ((unsigned)(v >> 32) != (unsigned)S_LEN);
      union { unsigned int u; float f; } hu; hu.u = (unsigned)v;
      hl[tid] = hu.f;
    }
    __syncthreads();
    const int j = tid >> 2, q = tid & 3;
    float sum = 0.f;
    const float4* w1v = (const float4*)(W1 + (size_t)j * 512 + q * 128);
#pragma unroll 8
    for (int k4 = 0; k4 < 32; ++k4) {
      const float4 v = w1v[k4];
      const int kb = q * 128 + k4 * 4;
      sum = __builtin_fmaf(v.x, hl[kb + 0], sum);
      sum = __builtin_fmaf(v.y, hl[kb + 1], sum);
      sum = __builtin_fmaf(v.z, hl[kb + 2], sum);
      sum = __builtin_fmaf(v.w, hl[kb + 3], sum);
    }
    sum += __shfl_xor(sum, 1);
    sum += __shfl_xor(sum, 2);
    if (q == 0) zl[j] = fsig(sum + b1[j]);
    __syncthreads();
    if (tid < 9) {
      float o = b2[tid];
      const float* w2r = W2 + tid * 128;
#pragma unroll 16
      for (int k = 0; k < 128; ++k) o = __builtin_fmaf(w2r[k], zl[k], o);
      out[tid] = fsig(o);
    }
  }
}

extern "C" void kernel_launch(void* const* d_in, const int* in_sizes, int n_in,
                              void* d_out, int out_size, void* d_ws, size_t ws_size,
                              hipStream_t stream) {
  const int*   x     = (const int*)d_in[0];
  const float* emb   = (const float*)d_in[1];
  const float* W_ih  = (const float*)d_in[2];
  const float* W_hh  = (const float*)d_in[3];
  const float* b_ih  = (const float*)d_in[4];
  const float* b_hh  = (const float*)d_in[5];
  const float* W1    = (const float*)d_in[6];
  const float* b1    = (const float*)d_in[7];
  const float* W2    = (const float*)d_in[8];
  const float* b2    = (const float*)d_in[9];
  float* out = (float*)d_out;

  const size_t gx_bytes = (size_t)S_LEN * 2048 * sizeof(unsigned short); // 64 MB
  const size_t fast_off = gx_bytes;                 // 8 KB
  const size_t slow_off = fast_off + 8192;          // 8 KB
  const size_t elec_off = slow_off + 8192;          // 64 B
  if (ws_size < elec_off + 64) return;  // fail visibly

  unsigned short* gxp    = (unsigned short*)d_ws;
  u64*            h_fast = (u64*)((char*)d_ws + fast_off);
  u64*            h_slow = (u64*)((char*)d_ws + slow_off);
  unsigned int*   elect  = (unsigned int*)((char*)d_ws + elec_off);

  // reset tags + election every launch (graph replays don't re-poison ws)
  (void)hipMemsetAsync((char*)d_ws + fast_off, 0, 8192 + 8192 + 64, stream);

  dim3 g1(S_LEN / 64, 2048 / 64);
  gx_gemm<<<g1, 256, 0, stream>>>(x, emb, W_ih, b_ih, b_hh, gxp);
  lstm_rec<<<NLAUNCH, NTHR, 0, stream>>>(W_hh, gxp, W1, b1, W2, b2, out,
                                         h_fast, h_slow, elect);
}

// Round 6
// 64245.697 us; speedup vs baseline: 1.7963x; 1.7963x over previous
//
#include <hip/hip_runtime.h>
#include <hip/hip_bf16.h>

// LSTM: V=50000, E=512, H=512, S=16384, batch=1.
// Phase 1: gx[t][unit][gate] = emb[x[t]].W_ih + (b_ih+b_hh), bf16.
// Phase 2: 16 persistent wgs x 512 thr. Each half-wave owns 2 units (4 units/wave,
//          4 gates each => gates computed in-wave, no LDS hand-off, no syncA).
//          h exchange: tag-in-data u64 agent atomics (no fences/flags); wave 0
//          polls 8 coalesced 512B lines, stages to double-buffered LDS; one
//          __syncthreads per step.
// Phase 3: head MLP on wg 0.

#define S_LEN 16384
#define NWG   16
#define NTHR  512

typedef unsigned long long u64;

static __device__ __forceinline__ float bf2f(unsigned int u16) {
  union { unsigned int i; float f; } v; v.i = u16 << 16; return v.f;
}
static __device__ __forceinline__ unsigned short f2bf(float f) {
  union { float f; unsigned int i; } v; v.f = f;
  unsigned int r = v.i + 0x7fffu + ((v.i >> 16) & 1u);
  return (unsigned short)(r >> 16);
}
static __device__ __forceinline__ float fsig(float x) { return 1.f / (1.f + __expf(-x)); }
static __device__ __forceinline__ float ftanh(float x) { return 2.f / (1.f + __expf(-2.f * x)) - 1.f; }

// h word slots: slot(k) = (k&7)*64 + (k>>3).
// Reader lane l, word i  <->  k = l*8+i  at slot i*64+l  (each i: 512B coalesced).
static __device__ __forceinline__ int hslot(int k) { return (k & 7) * 64 + (k >> 3); }
// LDS hbuf layout: h[k] at (k>>4)*20 + (k&15)  (80B-aligned rows, low conflict)
static __device__ __forceinline__ int haddr(int k) { return (k >> 4) * 20 + (k & 15); }

// ---------------- Phase 1: gx GEMM ----------------
__global__ __launch_bounds__(256, 2) void gx_gemm(
    const int* __restrict__ x, const float* __restrict__ emb,
    const float* __restrict__ W_ih, const float* __restrict__ b_ih,
    const float* __restrict__ b_hh, unsigned short* __restrict__ gx)
{
  __shared__ float As[64][40];
  __shared__ float Bs[64][40];
  __shared__ int   xs[64];

  const int tid = threadIdx.x;
  const int bm = blockIdx.x;
  const int bn = blockIdx.y;

  if (tid < 64) xs[tid] = x[bm * 64 + tid];
  __syncthreads();

  float acc[4][4] = {};
  const int r0 = (tid >> 4) * 4;
  const int c0 = tid & 15;

  for (int kc = 0; kc < 512; kc += 32) {
#pragma unroll
    for (int h = 0; h < 2; ++h) {
      const int v = tid + h * 256;
      const int row = v >> 3, k4 = v & 7;
      const float4 av = *(const float4*)(emb + (size_t)xs[row] * 512 + kc + k4 * 4);
      As[row][k4 * 4 + 0] = av.x; As[row][k4 * 4 + 1] = av.y;
      As[row][k4 * 4 + 2] = av.z; As[row][k4 * 4 + 3] = av.w;
      const float4 bv = *(const float4*)(W_ih + (size_t)(bn * 64 + row) * 512 + kc + k4 * 4);
      Bs[row][k4 * 4 + 0] = bv.x; Bs[row][k4 * 4 + 1] = bv.y;
      Bs[row][k4 * 4 + 2] = bv.z; Bs[row][k4 * 4 + 3] = bv.w;
    }
    __syncthreads();
#pragma unroll
    for (int k4 = 0; k4 < 8; ++k4) {
      float4 a[4], b[4];
#pragma unroll
      for (int i = 0; i < 4; ++i) a[i] = *(const float4*)&As[r0 + i][k4 * 4];
#pragma unroll
      for (int j = 0; j < 4; ++j) b[j] = *(const float4*)&Bs[c0 + j * 16][k4 * 4];
#pragma unroll
      for (int i = 0; i < 4; ++i)
#pragma unroll
        for (int j = 0; j < 4; ++j) {
          acc[i][j] = __builtin_fmaf(a[i].x, b[j].x, acc[i][j]);
          acc[i][j] = __builtin_fmaf(a[i].y, b[j].y, acc[i][j]);
          acc[i][j] = __builtin_fmaf(a[i].z, b[j].z, acc[i][j]);
          acc[i][j] = __builtin_fmaf(a[i].w, b[j].w, acc[i][j]);
        }
    }
    __syncthreads();
  }

  // layout [t][unit][gate]: dst = t*2048 + (c&511)*4 + (c>>9)
#pragma unroll
  for (int j = 0; j < 4; ++j) {
    const int c = bn * 64 + c0 + j * 16;
    const float bias = b_ih[c] + b_hh[c];
    const size_t dstc = (size_t)(c & 511) * 4 + (size_t)(c >> 9);
#pragma unroll
    for (int i = 0; i < 4; ++i) {
      const size_t t = (size_t)bm * 64 + r0 + i;
      gx[t * 2048 + dstc] = f2bf(acc[i][j] + bias);
    }
  }
}

// ---------------- Phase 2: persistent recurrence ----------------
__global__ __launch_bounds__(NTHR, 1) void lstm_rec(
    const float* __restrict__ W_hh, const unsigned short* __restrict__ gx,
    const float* __restrict__ W1, const float* __restrict__ b1,
    const float* __restrict__ W2, const float* __restrict__ b2,
    float* __restrict__ out,
    u64* __restrict__ h_glob)   // [2][512] (tag<<32 | f32 bits)
{
  const int tid  = threadIdx.x;
  const int w    = blockIdx.x;
  const int s    = tid & 31;          // K-slice: k in [s*16, s*16+16)
  const int half = (tid >> 5) & 1;
  const int wv   = tid >> 6;          // wave 0..7
  const int ubase = w * 32 + wv * 4 + half * 2;  // this half-wave's 2 units

  // weights in VGPRs: 8 rows x 16 k. rows q: unit=ubase+(q>>2), gate=q&3.
  float wreg[8][16];
#pragma unroll
  for (int q = 0; q < 8; ++q) {
    const int row = (q & 3) * 512 + ubase + (q >> 2);
    const float* src = W_hh + (size_t)row * 512 + s * 16;
#pragma unroll
    for (int i4 = 0; i4 < 4; ++i4) {
      const float4 vv = *(const float4*)(src + i4 * 4);
      wreg[q][i4 * 4 + 0] = vv.x; wreg[q][i4 * 4 + 1] = vv.y;
      wreg[q][i4 * 4 + 2] = vv.z; wreg[q][i4 * 4 + 3] = vv.w;
    }
  }

  __shared__ float hbuf[2][640];       // h[k] at haddr(k), double-buffered

  float c0 = 0.f, c1 = 0.f;            // cell states (s==0 lanes, units ubase, ubase+1)
  float h_reg[16];
#pragma unroll
  for (int i = 0; i < 16; ++i) h_reg[i] = 0.f;

  // gx pipeline (s==0 lanes): uint4 = 8 bf16 = gates of units ubase, ubase+1
  uint4 g_cur = {0,0,0,0}, g_nxt = {0,0,0,0};
  if (s == 0) {
    g_cur = *(const uint4*)(gx + (size_t)0 * 2048 + ubase * 4);
    g_nxt = *(const uint4*)(gx + (size_t)1 * 2048 + ubase * 4);
  }

  for (int t = 0; t < S_LEN; ++t) {
    uint4 g_new = {0,0,0,0};
    if (s == 0 && t + 2 < S_LEN)
      g_new = *(const uint4*)(gx + (size_t)(t + 2) * 2048 + ubase * 4);

    // partial dots + butterfly over the 32-lane half
    float acc[8];
#pragma unroll
    for (int q = 0; q < 8; ++q) {
      float a = 0.f;
#pragma unroll
      for (int i = 0; i < 16; ++i) a = __builtin_fmaf(wreg[q][i], h_reg[i], a);
      acc[q] = a;
    }
#pragma unroll
    for (int q = 0; q < 8; ++q) {
      float a = acc[q];
      a += __shfl_xor(a, 1);
      a += __shfl_xor(a, 2);
      a += __shfl_xor(a, 4);
      a += __shfl_xor(a, 8);
      a += __shfl_xor(a, 16);
      acc[q] = a;
    }

    const int buf = (t + 1) & 1;
    if (s == 0) {
      // unit ubase: acc[0..3] = i,f,g,o ; unit ubase+1: acc[4..7]
      const float pi0 = acc[0] + bf2f(g_cur.x & 0xffffu);
      const float pf0 = acc[1] + bf2f(g_cur.x >> 16);
      const float pg0 = acc[2] + bf2f(g_cur.y & 0xffffu);
      const float po0 = acc[3] + bf2f(g_cur.y >> 16);
      const float pi1 = acc[4] + bf2f(g_cur.z & 0xffffu);
      const float pf1 = acc[5] + bf2f(g_cur.z >> 16);
      const float pg1 = acc[6] + bf2f(g_cur.w & 0xffffu);
      const float po1 = acc[7] + bf2f(g_cur.w >> 16);
      c0 = fsig(pf0) * c0 + fsig(pi0) * ftanh(pg0);
      c1 = fsig(pf1) * c1 + fsig(pi1) * ftanh(pg1);
      const float h0 = fsig(po0) * ftanh(c0);
      const float h1 = fsig(po1) * ftanh(c1);

      union { float f; unsigned int u; } a0, a1; a0.f = h0; a1.f = h1;
      const u64 tg = (u64)(unsigned)(t + 1) << 32;
      __hip_atomic_store(&h_glob[buf * 512 + hslot(ubase)],     tg | (u64)a0.u,
                         __ATOMIC_RELAXED, __HIP_MEMORY_SCOPE_AGENT);
      __hip_atomic_store(&h_glob[buf * 512 + hslot(ubase + 1)], tg | (u64)a1.u,
                         __ATOMIC_RELAXED, __HIP_MEMORY_SCOPE_AGENT);
    }

    if (t + 1 < S_LEN) {
      if (tid < 64) {
        // wave 0 polls all 512 words: lane l covers k = l*8 .. l*8+7
        const u64* hb = h_glob + buf * 512;
        const unsigned want = (unsigned)(t + 1);
        u64 v[8];
        for (;;) {
#pragma unroll
          for (int i = 0; i < 8; ++i)
            v[i] = __hip_atomic_load(&hb[i * 64 + tid],
                                     __ATOMIC_RELAXED, __HIP_MEMORY_SCOPE_AGENT);
          bool ok = true;
#pragma unroll
          for (int i = 0; i < 8; ++i) ok &= ((unsigned)(v[i] >> 32) == want);
          if (__all(ok)) break;
        }
#pragma unroll
        for (int i = 0; i < 8; ++i) {
          union { unsigned int u; float f; } hu; hu.u = (unsigned)v[i];
          hbuf[buf][haddr(tid * 8 + i)] = hu.f;
        }
      }
      __syncthreads();
#pragma unroll
      for (int i = 0; i < 16; ++i)
        h_reg[i] = hbuf[buf][s * 20 + i];
    }

    g_cur = g_nxt; g_nxt = g_new;
  }

  // ---------------- Phase 3: head (wg 0) ----------------
  if (w == 0) {
    __shared__ float hl[512];
    __shared__ float zl[128];
    {
      // final h_S: tag S_LEN in buf 0 (S even)
      const int slot = hslot(tid);
      u64 v;
      do {
        v = __hip_atomic_load(&h_glob[slot], __ATOMIC_RELAXED, __HIP_MEMORY_SCOPE_AGENT);
      } while ((unsigned)(v >> 32) != (unsigned)S_LEN);
      union { unsigned int u; float f; } hu; hu.u = (unsigned)v;
      hl[tid] = hu.f;
    }
    __syncthreads();
    const int j = tid >> 2, q = tid & 3;
    float sum = 0.f;
    const float4* w1v = (const float4*)(W1 + (size_t)j * 512 + q * 128);
#pragma unroll 8
    for (int k4 = 0; k4 < 32; ++k4) {
      const float4 v = w1v[k4];
      const int kb = q * 128 + k4 * 4;
      sum = __builtin_fmaf(v.x, hl[kb + 0], sum);
      sum = __builtin_fmaf(v.y, hl[kb + 1], sum);
      sum = __builtin_fmaf(v.z, hl[kb + 2], sum);
      sum = __builtin_fmaf(v.w, hl[kb + 3], sum);
    }
    sum += __shfl_xor(sum, 1);
    sum += __shfl_xor(sum, 2);
    if (q == 0) zl[j] = fsig(sum + b1[j]);
    __syncthreads();
    if (tid < 9) {
      float o = b2[tid];
      const float* w2r = W2 + tid * 128;
#pragma unroll 16
      for (int k = 0; k < 128; ++k) o = __builtin_fmaf(w2r[k], zl[k], o);
      out[tid] = fsig(o);
    }
  }
}

extern "C" void kernel_launch(void* const* d_in, const int* in_sizes, int n_in,
                              void* d_out, int out_size, void* d_ws, size_t ws_size,
                              hipStream_t stream) {
  const int*   x     = (const int*)d_in[0];
  const float* emb   = (const float*)d_in[1];
  const float* W_ih  = (const float*)d_in[2];
  const float* W_hh  = (const float*)d_in[3];
  const float* b_ih  = (const float*)d_in[4];
  const float* b_hh  = (const float*)d_in[5];
  const float* W1    = (const float*)d_in[6];
  const float* b1    = (const float*)d_in[7];
  const float* W2    = (const float*)d_in[8];
  const float* b2    = (const float*)d_in[9];
  float* out = (float*)d_out;

  const size_t gx_bytes = (size_t)S_LEN * 2048 * sizeof(unsigned short); // 64 MB
  const size_t h_off    = gx_bytes;
  if (ws_size < h_off + 2 * 512 * sizeof(u64)) return;  // fail visibly

  unsigned short* gxp    = (unsigned short*)d_ws;
  u64*            h_glob = (u64*)((char*)d_ws + h_off);

  // tags must be reset every launch (graph replays do not re-poison d_ws)
  (void)hipMemsetAsync(h_glob, 0, 2 * 512 * sizeof(u64), stream);

  dim3 g1(S_LEN / 64, 2048 / 64);
  gx_gemm<<<g1, 256, 0, stream>>>(x, emb, W_ih, b_ih, b_hh, gxp);
  lstm_rec<<<NWG, NTHR, 0, stream>>>(W_hh, gxp, W1, b1, W2, b2, out, h_glob);
}

// Round 7
// 56497.314 us; speedup vs baseline: 2.0427x; 1.1371x over previous
//
#include <hip/hip_runtime.h>
#include <hip/hip_bf16.h>

// LSTM: V=50000, E=512, H=512, S=16384, batch=1.
// Phase 1: gx[t][unit][gate] = emb[x[t]].W_ih + (b_ih+b_hh), bf16.
// Phase 2: 16 persistent wgs x 512 thr. Half-wave owns 2 units; gates in-wave.
//          h exchange: tag-in-data u64, LINEAR layout (wg-exclusive cache lines),
//          producer stores condensed via LDS stage -> wave0 issues 2 line-wide
//          store instructions; wave0 polls coalesced; conflict-free LDS bcast.
// Phase 3: head MLP on wg 0.

#define S_LEN 16384
#define NWG   16
#define NTHR  512

typedef unsigned long long u64;

static __device__ __forceinline__ float bf2f(unsigned int u16) {
  union { unsigned int i; float f; } v; v.i = u16 << 16; return v.f;
}
static __device__ __forceinline__ unsigned short f2bf(float f) {
  union { float f; unsigned int i; } v; v.f = f;
  unsigned int r = v.i + 0x7fffu + ((v.i >> 16) & 1u);
  return (unsigned short)(r >> 16);
}
static __device__ __forceinline__ float fsig(float x) { return 1.f / (1.f + __expf(-x)); }
static __device__ __forceinline__ float ftanh(float x) { return 2.f / (1.f + __expf(-2.f * x)) - 1.f; }

// LDS hbuf: h[k] at k + (k>>4)  (stride-17 rows: bank-conflict-free)
static __device__ __forceinline__ int haddr(int k) { return k + (k >> 4); }

// ---------------- Phase 1: gx GEMM ----------------
__global__ __launch_bounds__(256, 2) void gx_gemm(
    const int* __restrict__ x, const float* __restrict__ emb,
    const float* __restrict__ W_ih, const float* __restrict__ b_ih,
    const float* __restrict__ b_hh, unsigned short* __restrict__ gx)
{
  __shared__ float As[64][40];
  __shared__ float Bs[64][40];
  __shared__ int   xs[64];

  const int tid = threadIdx.x;
  const int bm = blockIdx.x;
  const int bn = blockIdx.y;

  if (tid < 64) xs[tid] = x[bm * 64 + tid];
  __syncthreads();

  float acc[4][4] = {};
  const int r0 = (tid >> 4) * 4;
  const int c0 = tid & 15;

  for (int kc = 0; kc < 512; kc += 32) {
#pragma unroll
    for (int h = 0; h < 2; ++h) {
      const int v = tid + h * 256;
      const int row = v >> 3, k4 = v & 7;
      const float4 av = *(const float4*)(emb + (size_t)xs[row] * 512 + kc + k4 * 4);
      As[row][k4 * 4 + 0] = av.x; As[row][k4 * 4 + 1] = av.y;
      As[row][k4 * 4 + 2] = av.z; As[row][k4 * 4 + 3] = av.w;
      const float4 bv = *(const float4*)(W_ih + (size_t)(bn * 64 + row) * 512 + kc + k4 * 4);
      Bs[row][k4 * 4 + 0] = bv.x; Bs[row][k4 * 4 + 1] = bv.y;
      Bs[row][k4 * 4 + 2] = bv.z; Bs[row][k4 * 4 + 3] = bv.w;
    }
    __syncthreads();
#pragma unroll
    for (int k4 = 0; k4 < 8; ++k4) {
      float4 a[4], b[4];
#pragma unroll
      for (int i = 0; i < 4; ++i) a[i] = *(const float4*)&As[r0 + i][k4 * 4];
#pragma unroll
      for (int j = 0; j < 4; ++j) b[j] = *(const float4*)&Bs[c0 + j * 16][k4 * 4];
#pragma unroll
      for (int i = 0; i < 4; ++i)
#pragma unroll
        for (int j = 0; j < 4; ++j) {
          acc[i][j] = __builtin_fmaf(a[i].x, b[j].x, acc[i][j]);
          acc[i][j] = __builtin_fmaf(a[i].y, b[j].y, acc[i][j]);
          acc[i][j] = __builtin_fmaf(a[i].z, b[j].z, acc[i][j]);
          acc[i][j] = __builtin_fmaf(a[i].w, b[j].w, acc[i][j]);
        }
    }
    __syncthreads();
  }

  // layout [t][unit][gate]: dst = t*2048 + (c&511)*4 + (c>>9)
#pragma unroll
  for (int j = 0; j < 4; ++j) {
    const int c = bn * 64 + c0 + j * 16;
    const float bias = b_ih[c] + b_hh[c];
    const size_t dstc = (size_t)(c & 511) * 4 + (size_t)(c >> 9);
#pragma unroll
    for (int i = 0; i < 4; ++i) {
      const size_t t = (size_t)bm * 64 + r0 + i;
      gx[t * 2048 + dstc] = f2bf(acc[i][j] + bias);
    }
  }
}

// ---------------- Phase 2: persistent recurrence ----------------
__global__ __launch_bounds__(NTHR, 1) void lstm_rec(
    const float* __restrict__ W_hh, const unsigned short* __restrict__ gx,
    const float* __restrict__ W1, const float* __restrict__ b1,
    const float* __restrict__ W2, const float* __restrict__ b2,
    float* __restrict__ out,
    u64* __restrict__ h_glob)   // [2][512] (tag<<32 | f32 bits), LINEAR by unit
{
  const int tid  = threadIdx.x;
  const int w    = blockIdx.x;
  const int s    = tid & 31;          // K-slice: k in [s*16, s*16+16)
  const int half = (tid >> 5) & 1;
  const int wv   = tid >> 6;          // wave 0..7
  const int ubase = w * 32 + wv * 4 + half * 2;  // this half-wave's 2 units
  const int ulocal = wv * 4 + half * 2;          // 0..30 even

  // weights in VGPRs: 8 rows x 16 k. rows q: unit=ubase+(q>>2), gate=q&3.
  float wreg[8][16];
#pragma unroll
  for (int q = 0; q < 8; ++q) {
    const int row = (q & 3) * 512 + ubase + (q >> 2);
    const float* src = W_hh + (size_t)row * 512 + s * 16;
#pragma unroll
    for (int i4 = 0; i4 < 4; ++i4) {
      const float4 vv = *(const float4*)(src + i4 * 4);
      wreg[q][i4 * 4 + 0] = vv.x; wreg[q][i4 * 4 + 1] = vv.y;
      wreg[q][i4 * 4 + 2] = vv.z; wreg[q][i4 * 4 + 3] = vv.w;
    }
  }

  __shared__ float hbuf[2][544];       // h[k] at haddr(k)
  __shared__ u64   stage[32];          // this wg's tagged h words

  float c0 = 0.f, c1 = 0.f;            // cell states (s==0 lanes)
  float h_reg[16];
#pragma unroll
  for (int i = 0; i < 16; ++i) h_reg[i] = 0.f;

  // gx pipeline (s==0 lanes): uint4 = 8 bf16 = gates of units ubase, ubase+1
  uint4 g_cur = {0,0,0,0}, g_nxt = {0,0,0,0};
  if (s == 0) {
    g_cur = *(const uint4*)(gx + (size_t)0 * 2048 + ubase * 4);
    g_nxt = *(const uint4*)(gx + (size_t)1 * 2048 + ubase * 4);
  }

  for (int t = 0; t < S_LEN; ++t) {
    uint4 g_new = {0,0,0,0};
    if (s == 0 && t + 2 < S_LEN)
      g_new = *(const uint4*)(gx + (size_t)(t + 2) * 2048 + ubase * 4);

    // partial dots + butterfly over the 32-lane half
    float acc[8];
#pragma unroll
    for (int q = 0; q < 8; ++q) {
      float a = 0.f;
#pragma unroll
      for (int i = 0; i < 16; ++i) a = __builtin_fmaf(wreg[q][i], h_reg[i], a);
      acc[q] = a;
    }
#pragma unroll
    for (int q = 0; q < 8; ++q) {
      float a = acc[q];
      a += __shfl_xor(a, 1);
      a += __shfl_xor(a, 2);
      a += __shfl_xor(a, 4);
      a += __shfl_xor(a, 8);
      a += __shfl_xor(a, 16);
      acc[q] = a;
    }

    const int buf = (t + 1) & 1;
    if (s == 0) {
      const float pi0 = acc[0] + bf2f(g_cur.x & 0xffffu);
      const float pf0 = acc[1] + bf2f(g_cur.x >> 16);
      const float pg0 = acc[2] + bf2f(g_cur.y & 0xffffu);
      const float po0 = acc[3] + bf2f(g_cur.y >> 16);
      const float pi1 = acc[4] + bf2f(g_cur.z & 0xffffu);
      const float pf1 = acc[5] + bf2f(g_cur.z >> 16);
      const float pg1 = acc[6] + bf2f(g_cur.w & 0xffffu);
      const float po1 = acc[7] + bf2f(g_cur.w >> 16);
      c0 = fsig(pf0) * c0 + fsig(pi0) * ftanh(pg0);
      c1 = fsig(pf1) * c1 + fsig(pi1) * ftanh(pg1);
      const float h0 = fsig(po0) * ftanh(c0);
      const float h1 = fsig(po1) * ftanh(c1);
      union { float f; unsigned int u; } a0, a1; a0.f = h0; a1.f = h1;
      const u64 tg = (u64)(unsigned)(t + 1) << 32;
      ulonglong2 pk; pk.x = tg | (u64)a0.u; pk.y = tg | (u64)a1.u;
      *(ulonglong2*)&stage[ulocal] = pk;   // 16B aligned (ulocal even)
    }
    __syncthreads();  // S1 — stage complete

    if (tid < 64) {
      // condensed publish: 2 instructions, each 16 lanes x 8B = one 128B line
      if (tid < 16) {
        const u64 sv0 = stage[tid];
        const u64 sv1 = stage[tid + 16];
        __hip_atomic_store(&h_glob[buf * 512 + w * 32 + tid], sv0,
                           __ATOMIC_RELAXED, __HIP_MEMORY_SCOPE_AGENT);
        __hip_atomic_store(&h_glob[buf * 512 + w * 32 + 16 + tid], sv1,
                           __ATOMIC_RELAXED, __HIP_MEMORY_SCOPE_AGENT);
      }
      // coalesced poll: lane l checks words 128j + 2l + m (j=0..3, m=0..1)
      if (t + 1 < S_LEN) {
        const u64* hb = h_glob + buf * 512;
        const unsigned want = (unsigned)(t + 1);
        u64 v[8];
        for (;;) {
#pragma unroll
          for (int j = 0; j < 4; ++j) {
            v[j * 2]     = __hip_atomic_load(&hb[j * 128 + tid * 2],
                             __ATOMIC_RELAXED, __HIP_MEMORY_SCOPE_AGENT);
            v[j * 2 + 1] = __hip_atomic_load(&hb[j * 128 + tid * 2 + 1],
                             __ATOMIC_RELAXED, __HIP_MEMORY_SCOPE_AGENT);
          }
          bool ok = true;
#pragma unroll
          for (int i = 0; i < 8; ++i) ok &= ((unsigned)(v[i] >> 32) == want);
          if (__all(ok)) break;
        }
#pragma unroll
        for (int j = 0; j < 4; ++j) {
#pragma unroll
          for (int m = 0; m < 2; ++m) {
            const int k = j * 128 + tid * 2 + m;
            union { unsigned int u; float f; } hu; hu.u = (unsigned)v[j * 2 + m];
            hbuf[buf][haddr(k)] = hu.f;
          }
        }
      }
    }
    __syncthreads();  // S2 — h_{t+1} staged in LDS

    if (t + 1 < S_LEN) {
      const int base = s * 17;   // haddr(s*16 + i) = s*17 + i
#pragma unroll
      for (int i = 0; i < 16; ++i)
        h_reg[i] = hbuf[buf][base + i];
    }

    g_cur = g_nxt; g_nxt = g_new;
  }

  // ---------------- Phase 3: head (wg 0) ----------------
  if (w == 0) {
    __shared__ float hl[512];
    __shared__ float zl[128];
    {
      // final h_S: tag S_LEN in buf 0 (S even), linear word tid
      u64 v;
      do {
        v = __hip_atomic_load(&h_glob[tid], __ATOMIC_RELAXED, __HIP_MEMORY_SCOPE_AGENT);
      } while ((unsigned)(v >> 32) != (unsigned)S_LEN);
      union { unsigned int u; float f; } hu; hu.u = (unsigned)v;
      hl[tid] = hu.f;
    }
    __syncthreads();
    const int j = tid >> 2, q = tid & 3;
    float sum = 0.f;
    const float4* w1v = (const float4*)(W1 + (size_t)j * 512 + q * 128);
#pragma unroll 8
    for (int k4 = 0; k4 < 32; ++k4) {
      const float4 v = w1v[k4];
      const int kb = q * 128 + k4 * 4;
      sum = __builtin_fmaf(v.x, hl[kb + 0], sum);
      sum = __builtin_fmaf(v.y, hl[kb + 1], sum);
      sum = __builtin_fmaf(v.z, hl[kb + 2], sum);
      sum = __builtin_fmaf(v.w, hl[kb + 3], sum);
    }
    sum += __shfl_xor(sum, 1);
    sum += __shfl_xor(sum, 2);
    if (q == 0) zl[j] = fsig(sum + b1[j]);
    __syncthreads();
    if (tid < 9) {
      float o = b2[tid];
      const float* w2r = W2 + tid * 128;
#pragma unroll 16
      for (int k = 0; k < 128; ++k) o = __builtin_fmaf(w2r[k], zl[k], o);
      out[tid] = fsig(o);
    }
  }
}

extern "C" void kernel_launch(void* const* d_in, const int* in_sizes, int n_in,
                              void* d_out, int out_size, void* d_ws, size_t ws_size,
                              hipStream_t stream) {
  const int*   x     = (const int*)d_in[0];
  const float* emb   = (const float*)d_in[1];
  const float* W_ih  = (const float*)d_in[2];
  const float* W_hh  = (const float*)d_in[3];
  const float* b_ih  = (const float*)d_in[4];
  const float* b_hh  = (const float*)d_in[5];
  const float* W1    = (const float*)d_in[6];
  const float* b1    = (const float*)d_in[7];
  const float* W2    = (const float*)d_in[8];
  const float* b2    = (const float*)d_in[9];
  float* out = (float*)d_out;

  const size_t gx_bytes = (size_t)S_LEN * 2048 * sizeof(unsigned short); // 64 MB
  const size_t h_off    = gx_bytes;
  if (ws_size < h_off + 2 * 512 * sizeof(u64)) return;  // fail visibly

  unsigned short* gxp    = (unsigned short*)d_ws;
  u64*            h_glob = (u64*)((char*)d_ws + h_off);

  // tags must be reset every launch (graph replays do not re-poison d_ws)
  (void)hipMemsetAsync(h_glob, 0, 2 * 512 * sizeof(u64), stream);

  dim3 g1(S_LEN / 64, 2048 / 64);
  gx_gemm<<<g1, 256, 0, stream>>>(x, emb, W_ih, b_ih, b_hh, gxp);
  lstm_rec<<<NWG, NTHR, 0, stream>>>(W_hh, gxp, W1, b1, W2, b2, out, h_glob);
}

// Round 9
// 45721.799 us; speedup vs baseline: 2.5241x; 1.2357x over previous
//
#include <hip/hip_runtime.h>
#include <hip/hip_bf16.h>

// LSTM: V=50000, E=512, H=512, S=16384, batch=1.
// Phase 1: gx[t][unit][gate] = emb[x[t]].W_ih + (b_ih+b_hh), bf16.
// Phase 2: 128 wgs launched; first 16 registering on one XCD participate (rest exit).
//          Weights pinned in VGPRs via inline-asm loads. h exchange = tag-in-data
//          u64, linear wg-exclusive lines. FAST path: sc0 (same-XCD L2) stores/
//          polls, validated once by a 16-round handshake; else R7 agent path.
// Phase 3: head MLP on rank 0.

#define S_LEN 16384
#define NWG   16
#define NLAUNCH 128
#define NTHR  512

typedef unsigned long long u64;
typedef unsigned int uint4v __attribute__((ext_vector_type(4)));
typedef float float4v __attribute__((ext_vector_type(4)));

static __device__ __forceinline__ float bf2f(unsigned int u16) {
  union { unsigned int i; float f; } v; v.i = u16 << 16; return v.f;
}
static __device__ __forceinline__ unsigned short f2bf(float f) {
  union { float f; unsigned int i; } v; v.f = f;
  unsigned int r = v.i + 0x7fffu + ((v.i >> 16) & 1u);
  return (unsigned short)(r >> 16);
}
static __device__ __forceinline__ float fsig(float x) { return 1.f / (1.f + __expf(-x)); }
static __device__ __forceinline__ float ftanh(float x) { return 2.f / (1.f + __expf(-2.f * x)) - 1.f; }

// LDS hbuf: h[k] at k + (k>>4)  (stride-17 rows: conflict-free)
static __device__ __forceinline__ int haddr(int k) { return k + (k >> 4); }

// ---- sc0 primitives (bypass L1, land/hit in the CU's XCD L2) ----
static __device__ __forceinline__ u64 ld_sc0(const u64* p) {
  u64 v;
  asm volatile("global_load_dwordx2 %0, %1, off sc0\n\ts_waitcnt vmcnt(0)"
               : "=v"(v) : "v"((u64)p) : "memory");
  return v;
}
static __device__ __forceinline__ void st_sc0(u64* p, u64 w) {
  asm volatile("global_store_dwordx2 %0, %1, off sc0"
               :: "v"((u64)p), "v"(w) : "memory");
}
static __device__ __forceinline__ void st_sc0_x4(u64* p, uint4v q) {
  asm volatile("global_store_dwordx4 %0, %1, off sc0"
               :: "v"((u64)p), "v"(q) : "memory");
}
static __device__ __forceinline__ void poll8_sc0(const u64* base, int lane, u64 v[8]) {
  u64 a = (u64)base + (u64)lane * 8ull;
  asm volatile(
      "global_load_dwordx2 %[v0], %[ad], off sc0\n\t"
      "global_load_dwordx2 %[v1], %[ad], off offset:512 sc0\n\t"
      "global_load_dwordx2 %[v2], %[ad], off offset:1024 sc0\n\t"
      "global_load_dwordx2 %[v3], %[ad], off offset:1536 sc0\n\t"
      "global_load_dwordx2 %[v4], %[ad], off offset:2048 sc0\n\t"
      "global_load_dwordx2 %[v5], %[ad], off offset:2560 sc0\n\t"
      "global_load_dwordx2 %[v6], %[ad], off offset:3072 sc0\n\t"
      "global_load_dwordx2 %[v7], %[ad], off offset:3584 sc0\n\t"
      "s_waitcnt vmcnt(0)"
      : [v0] "=&v"(v[0]), [v1] "=&v"(v[1]), [v2] "=&v"(v[2]), [v3] "=&v"(v[3]),
        [v4] "=&v"(v[4]), [v5] "=&v"(v[5]), [v6] "=&v"(v[6]), [v7] "=&v"(v[7])
      : [ad] "v"(a)
      : "memory");
}

// ---------------- Phase 1: gx GEMM ----------------
__global__ __launch_bounds__(256, 2) void gx_gemm(
    const int* __restrict__ x, const float* __restrict__ emb,
    const float* __restrict__ W_ih, const float* __restrict__ b_ih,
    const float* __restrict__ b_hh, unsigned short* __restrict__ gx)
{
  __shared__ float As[64][40];
  __shared__ float Bs[64][40];
  __shared__ int   xs[64];

  const int tid = threadIdx.x;
  const int bm = blockIdx.x;
  const int bn = blockIdx.y;

  if (tid < 64) xs[tid] = x[bm * 64 + tid];
  __syncthreads();

  float acc[4][4] = {};
  const int r0 = (tid >> 4) * 4;
  const int c0 = tid & 15;

  for (int kc = 0; kc < 512; kc += 32) {
#pragma unroll
    for (int h = 0; h < 2; ++h) {
      const int v = tid + h * 256;
      const int row = v >> 3, k4 = v & 7;
      const float4 av = *(const float4*)(emb + (size_t)xs[row] * 512 + kc + k4 * 4);
      As[row][k4 * 4 + 0] = av.x; As[row][k4 * 4 + 1] = av.y;
      As[row][k4 * 4 + 2] = av.z; As[row][k4 * 4 + 3] = av.w;
      const float4 bv = *(const float4*)(W_ih + (size_t)(bn * 64 + row) * 512 + kc + k4 * 4);
      Bs[row][k4 * 4 + 0] = bv.x; Bs[row][k4 * 4 + 1] = bv.y;
      Bs[row][k4 * 4 + 2] = bv.z; Bs[row][k4 * 4 + 3] = bv.w;
    }
    __syncthreads();
#pragma unroll
    for (int k4 = 0; k4 < 8; ++k4) {
      float4 a[4], b[4];
#pragma unroll
      for (int i = 0; i < 4; ++i) a[i] = *(const float4*)&As[r0 + i][k4 * 4];
#pragma unroll
      for (int j = 0; j < 4; ++j) b[j] = *(const float4*)&Bs[c0 + j * 16][k4 * 4];
#pragma unroll
      for (int i = 0; i < 4; ++i)
#pragma unroll
        for (int j = 0; j < 4; ++j) {
          acc[i][j] = __builtin_fmaf(a[i].x, b[j].x, acc[i][j]);
          acc[i][j] = __builtin_fmaf(a[i].y, b[j].y, acc[i][j]);
          acc[i][j] = __builtin_fmaf(a[i].z, b[j].z, acc[i][j]);
          acc[i][j] = __builtin_fmaf(a[i].w, b[j].w, acc[i][j]);
        }
    }
    __syncthreads();
  }

  // layout [t][unit][gate]: dst = t*2048 + (c&511)*4 + (c>>9)
#pragma unroll
  for (int j = 0; j < 4; ++j) {
    const int c = bn * 64 + c0 + j * 16;
    const float bias = b_ih[c] + b_hh[c];
    const size_t dstc = (size_t)(c & 511) * 4 + (size_t)(c >> 9);
#pragma unroll
    for (int i = 0; i < 4; ++i) {
      const size_t t = (size_t)bm * 64 + r0 + i;
      gx[t * 2048 + dstc] = f2bf(acc[i][j] + bias);
    }
  }
}

// ---------------- Phase 2: XCD-pinned recurrence ----------------
__global__ __launch_bounds__(NTHR, 1) void lstm_rec(
    const float* __restrict__ W_hh, const unsigned short* __restrict__ gx,
    const float* __restrict__ W1, const float* __restrict__ b1,
    const float* __restrict__ W2, const float* __restrict__ b2,
    float* __restrict__ out,
    u64* __restrict__ h_glob,   // [2][512] (tag<<32 | f32 bits), linear by unit
    u64* __restrict__ hs,       // [16] handshake tags
    unsigned int* __restrict__ elect,  // [8] cnt per xcd, [8]=winner+1
    unsigned int* __restrict__ ver)    // [0]=nfail [1]=ndone [2]=modeword
{
  const int tid = threadIdx.x;

  // ---- election: first NWG wgs registering on one XCD participate ----
  __shared__ int role_sh;
  if (tid == 0) {
    unsigned xcc;
    asm volatile("s_getreg_b32 %0, hwreg(HW_REG_XCC_ID)" : "=s"(xcc));
    xcc &= 7u;
    const unsigned r = __hip_atomic_fetch_add(&elect[xcc], 1u,
                         __ATOMIC_RELAXED, __HIP_MEMORY_SCOPE_AGENT);
    int role = -1;
    if (r < NWG) {
      if (r == NWG - 1) {
        unsigned exp = 0u;
        __hip_atomic_compare_exchange_strong(&elect[8], &exp, xcc + 1u,
            __ATOMIC_RELAXED, __ATOMIC_RELAXED, __HIP_MEMORY_SCOPE_AGENT);
      }
      unsigned wv_;
      do {
        wv_ = __hip_atomic_load(&elect[8], __ATOMIC_RELAXED, __HIP_MEMORY_SCOPE_AGENT);
        if (wv_ == 0u) __builtin_amdgcn_s_sleep(2);
      } while (wv_ == 0u);
      if (wv_ == xcc + 1u) role = (int)r;
    }
    role_sh = role;
  }
  __syncthreads();
  const int w = role_sh;
  if (w < 0) return;

  const int s    = tid & 31;          // K-slice: k in [s*16, s*16+16)
  const int half = (tid >> 5) & 1;
  const int wvi  = tid >> 6;          // wave 0..7
  const int ubase  = w * 32 + wvi * 4 + half * 2;
  const int ulocal = wvi * 4 + half * 2;

  // ---- weights pinned in VGPRs via asm loads (non-rematerializable) ----
  float4v wvv[32];
#pragma unroll
  for (int q = 0; q < 8; ++q) {
    const int row = (q & 3) * 512 + ubase + (q >> 2);
    const float* src = W_hh + (size_t)row * 512 + s * 16;
#pragma unroll
    for (int i4 = 0; i4 < 4; ++i4) {
      asm volatile("global_load_dwordx4 %0, %1, off\n\ts_waitcnt vmcnt(0)"
                   : "=v"(wvv[q * 4 + i4]) : "v"((u64)(src + i4 * 4)) : "memory");
    }
  }

  // ---- handshake: validate sc0 exchange with the real primitives ----
  __shared__ int mode_sh;
  if (tid < 64) {
    bool fastok = true;
    int budget = 20000;
    for (int round = 1; round <= 16 && fastok; ++round) {
      if (tid == 0)
        st_sc0(&hs[w], ((u64)(unsigned)round << 32) | (unsigned)w);
      bool ok = false;
      while (budget > 0) {
        --budget;
        u64 v = 0;
        if (tid < 16) v = ld_sc0(&hs[tid]);
        const bool lok = (tid < 16) ? ((unsigned)(v >> 32) >= (unsigned)round) : true;
        if (__all(lok)) { ok = true; break; }
      }
      if (!ok) fastok = false;
    }
    if (tid == 0) mode_sh = fastok ? 1 : 0;
  }
  __syncthreads();
  if (tid == 0) {
    const unsigned myfail = mode_sh ? 0u : 1u;
    __hip_atomic_fetch_add(&ver[0], myfail, __ATOMIC_RELAXED, __HIP_MEMORY_SCOPE_AGENT);
    __hip_atomic_fetch_add(&ver[1], 1u, __ATOMIC_RELEASE, __HIP_MEMORY_SCOPE_AGENT);
    if (w == 0) {
      while (__hip_atomic_load(&ver[1], __ATOMIC_ACQUIRE, __HIP_MEMORY_SCOPE_AGENT) < NWG) {}
      const unsigned nf = __hip_atomic_load(&ver[0], __ATOMIC_RELAXED, __HIP_MEMORY_SCOPE_AGENT);
      __hip_atomic_store(&ver[2], 0x100u | (nf == 0u ? 1u : 0u),
                         __ATOMIC_RELAXED, __HIP_MEMORY_SCOPE_AGENT);
    }
    unsigned mw;
    do {
      mw = __hip_atomic_load(&ver[2], __ATOMIC_RELAXED, __HIP_MEMORY_SCOPE_AGENT);
    } while (!(mw & 0x100u));
    mode_sh = (int)(mw & 1u);
  }
  __syncthreads();
  const int mode = mode_sh;   // uniform across all participants

  __shared__ float hbuf[2][544];
  __shared__ u64   stage[32];

  float c0 = 0.f, c1 = 0.f;
  float h_reg[16];
#pragma unroll
  for (int i = 0; i < 16; ++i) h_reg[i] = 0.f;

  uint4 g_cur = {0,0,0,0}, g_nxt = {0,0,0,0};
  if (s == 0) {
    g_cur = *(const uint4*)(gx + (size_t)0 * 2048 + ubase * 4);
    g_nxt = *(const uint4*)(gx + (size_t)1 * 2048 + ubase * 4);
  }

  for (int t = 0; t < S_LEN; ++t) {
    uint4 g_new = {0,0,0,0};
    if (s == 0 && t + 2 < S_LEN)
      g_new = *(const uint4*)(gx + (size_t)(t + 2) * 2048 + ubase * 4);

    float acc[8];
#pragma unroll
    for (int q = 0; q < 8; ++q) {
      float a = 0.f;
#pragma unroll
      for (int i4 = 0; i4 < 4; ++i4) {
        const float4v vv = wvv[q * 4 + i4];
        a = __builtin_fmaf(vv.x, h_reg[i4 * 4 + 0], a);
        a = __builtin_fmaf(vv.y, h_reg[i4 * 4 + 1], a);
        a = __builtin_fmaf(vv.z, h_reg[i4 * 4 + 2], a);
        a = __builtin_fmaf(vv.w, h_reg[i4 * 4 + 3], a);
      }
      acc[q] = a;
    }
#pragma unroll
    for (int q = 0; q < 8; ++q) {
      float a = acc[q];
      a += __shfl_xor(a, 1);
      a += __shfl_xor(a, 2);
      a += __shfl_xor(a, 4);
      a += __shfl_xor(a, 8);
      a += __shfl_xor(a, 16);
      acc[q] = a;
    }

    const int buf = (t + 1) & 1;
    if (s == 0) {
      const float pi0 = acc[0] + bf2f(g_cur.x & 0xffffu);
      const float pf0 = acc[1] + bf2f(g_cur.x >> 16);
      const float pg0 = acc[2] + bf2f(g_cur.y & 0xffffu);
      const float po0 = acc[3] + bf2f(g_cur.y >> 16);
      const float pi1 = acc[4] + bf2f(g_cur.z & 0xffffu);
      const float pf1 = acc[5] + bf2f(g_cur.z >> 16);
      const float pg1 = acc[6] + bf2f(g_cur.w & 0xffffu);
      const float po1 = acc[7] + bf2f(g_cur.w >> 16);
      c0 = fsig(pf0) * c0 + fsig(pi0) * ftanh(pg0);
      c1 = fsig(pf1) * c1 + fsig(pi1) * ftanh(pg1);
      const float h0 = fsig(po0) * ftanh(c0);
      const float h1 = fsig(po1) * ftanh(c1);
      union { float f; unsigned int u; } a0, a1; a0.f = h0; a1.f = h1;
      const unsigned tg = (unsigned)(t + 1);
      if (mode) {
        uint4v pk; pk.x = a0.u; pk.y = tg; pk.z = a1.u; pk.w = tg;
        st_sc0_x4(&h_glob[buf * 512 + w * 32 + ulocal], pk);
      } else {
        ulonglong2 pk;
        pk.x = ((u64)tg << 32) | (u64)a0.u;
        pk.y = ((u64)tg << 32) | (u64)a1.u;
        *(ulonglong2*)&stage[ulocal] = pk;
      }
    }
    if (!mode) __syncthreads();  // S1 (slow publish staging)

    if (tid < 64) {
      if (!mode && tid < 16) {
        __hip_atomic_store(&h_glob[buf * 512 + w * 32 + tid], stage[tid],
                           __ATOMIC_RELAXED, __HIP_MEMORY_SCOPE_AGENT);
        __hip_atomic_store(&h_glob[buf * 512 + w * 32 + 16 + tid], stage[tid + 16],
                           __ATOMIC_RELAXED, __HIP_MEMORY_SCOPE_AGENT);
      }
      if (t + 1 < S_LEN) {
        const u64* hb = h_glob + buf * 512;
        const unsigned want = (unsigned)(t + 1);
        u64 v[8];
        if (mode) {
          for (;;) {
            poll8_sc0(hb, tid, v);
            bool ok = true;
#pragma unroll
            for (int i = 0; i < 8; ++i) ok &= ((unsigned)(v[i] >> 32) >= want);
            if (__all(ok)) break;
          }
        } else {
          for (;;) {
#pragma unroll
            for (int i = 0; i < 8; ++i)
              v[i] = __hip_atomic_load(&hb[i * 64 + tid],
                                       __ATOMIC_RELAXED, __HIP_MEMORY_SCOPE_AGENT);
            bool ok = true;
#pragma unroll
            for (int i = 0; i < 8; ++i) ok &= ((unsigned)(v[i] >> 32) >= want);
            if (__all(ok)) break;
          }
        }
#pragma unroll
        for (int i = 0; i < 8; ++i) {
          union { unsigned int u; float f; } hu; hu.u = (unsigned)v[i];
          hbuf[buf][haddr(i * 64 + tid)] = hu.f;
        }
      }
    }
    __syncthreads();  // S2 — h_{t+1} staged in LDS

    if (t + 1 < S_LEN) {
      const int base = s * 17;
#pragma unroll
      for (int i = 0; i < 16; ++i)
        h_reg[i] = hbuf[buf][base + i];
    }

    g_cur = g_nxt; g_nxt = g_new;
  }

  // ---------------- Phase 3: head (rank 0) ----------------
  if (w == 0) {
    __shared__ float hl[512];
    __shared__ float zl[128];
    {
      u64 v;
      if (mode) {
        do { v = ld_sc0(&h_glob[tid]); } while ((unsigned)(v >> 32) != (unsigned)S_LEN);
      } else {
        do {
          v = __hip_atomic_load(&h_glob[tid], __ATOMIC_RELAXED, __HIP_MEMORY_SCOPE_AGENT);
        } while ((unsigned)(v >> 32) != (unsigned)S_LEN);
      }
      union { unsigned int u; float f; } hu; hu.u = (unsigned)v;
      hl[tid] = hu.f;
    }
    __syncthreads();
    const int j = tid >> 2, q = tid & 3;
    float sum = 0.f;
    const float4* w1v = (const float4*)(W1 + (size_t)j * 512 + q * 128);
#pragma unroll 8
    for (int k4 = 0; k4 < 32; ++k4) {
      const float4 v = w1v[k4];
      const int kb = q * 128 + k4 * 4;
      sum = __builtin_fmaf(v.x, hl[kb + 0], sum);
      sum = __builtin_fmaf(v.y, hl[kb + 1], sum);
      sum = __builtin_fmaf(v.z, hl[kb + 2], sum);
      sum = __builtin_fmaf(v.w, hl[kb + 3], sum);
    }
    sum += __shfl_xor(sum, 1);
    sum += __shfl_xor(sum, 2);
    if (q == 0) zl[j] = fsig(sum + b1[j]);
    __syncthreads();
    if (tid < 9) {
      float o = b2[tid];
      const float* w2r = W2 + tid * 128;
#pragma unroll 16
      for (int k = 0; k < 128; ++k) o = __builtin_fmaf(w2r[k], zl[k], o);
      out[tid] = fsig(o);
    }
  }
}

extern "C" void kernel_launch(void* const* d_in, const int* in_sizes, int n_in,
                              void* d_out, int out_size, void* d_ws, size_t ws_size,
                              hipStream_t stream) {
  const int*   x     = (const int*)d_in[0];
  const float* emb   = (const float*)d_in[1];
  const float* W_ih  = (const float*)d_in[2];
  const float* W_hh  = (const float*)d_in[3];
  const float* b_ih  = (const float*)d_in[4];
  const float* b_hh  = (const float*)d_in[5];
  const float* W1    = (const float*)d_in[6];
  const float* b1    = (const float*)d_in[7];
  const float* W2    = (const float*)d_in[8];
  const float* b2    = (const float*)d_in[9];
  float* out = (float*)d_out;

  const size_t gx_bytes = (size_t)S_LEN * 2048 * sizeof(unsigned short); // 64 MB
  const size_t h_off    = gx_bytes;                 // h_glob 8KB
  const size_t hs_off   = h_off + 8192;             // 128B
  const size_t el_off   = h_off + 8192 + 128;       // 36B (pad to 64)
  const size_t vr_off   = h_off + 8192 + 256;       // 12B
  if (ws_size < h_off + 16384) return;  // fail visibly

  unsigned short* gxp    = (unsigned short*)d_ws;
  u64*            h_glob = (u64*)((char*)d_ws + h_off);
  u64*            hsp    = (u64*)((char*)d_ws + hs_off);
  unsigned int*   elect  = (unsigned int*)((char*)d_ws + el_off);
  unsigned int*   ver    = (unsigned int*)((char*)d_ws + vr_off);

  // reset all sync state every launch (graph replays don't re-poison ws)
  (void)hipMemsetAsync((char*)d_ws + h_off, 0, 16384, stream);

  dim3 g1(S_LEN / 64, 2048 / 64);
  gx_gemm<<<g1, 256, 0, stream>>>(x, emb, W_ih, b_ih, b_hh, gxp);
  lstm_rec<<<NLAUNCH, NTHR, 0, stream>>>(W_hh, gxp, W1, b1, W2, b2, out,
                                         h_glob, hsp, elect, ver);
}